// Round 6
// baseline (299.869 us; speedup 1.0000x reference)
//
#include <hip/hip_runtime.h>
#include <stdint.h>

typedef _Float16 f16;
typedef _Float16 f16x8 __attribute__((ext_vector_type(8)));
typedef _Float16 f16x4 __attribute__((ext_vector_type(4)));
typedef float floatx4 __attribute__((ext_vector_type(4)));
typedef float floatx16 __attribute__((ext_vector_type(16)));

#define TT 64
#define CDIM 384
#define HH 64
#define NKK 6           // K-loop iterations (BK=64)
#define LDP 72          // f16 LDS row stride (144 B, 16B-aligned)
#define ARENA 4608      // f16 elems per tail arena (64*LDP)
#define CHUNKB 24576    // bytes per BK=64 W chunk: 24 frag-groups * 64 lanes * 16 B
#define CHH 12288       // f16 elems per chunk
#define SCALE 0.05103103630798288f   // 384^-0.5 (reference scales by C^-0.5)

// Pre-pass: Wq/Wk/Wv -> fp16 in 32x32x16 MFMA B-fragment order.
// frag idx = ((ks*3 + p)*2 + t2)*64 + lane ; lane holds
// W_p[k = ks*16 + (lane>>5)*8 + j][n = t2*32 + (lane&31)], j=0..7.
__global__ void prep_w(const float* __restrict__ Wq,
                       const float* __restrict__ Wk,
                       const float* __restrict__ Wv,
                       f16* __restrict__ wf) {
    int t = blockIdx.x * 256 + threadIdx.x;
    if (t >= 24 * 3 * 2 * 64) return;
    int lane = t & 63;
    int t2   = (t >> 6) & 1;
    int g    = t >> 7;          // ks*3 + p
    int p    = g % 3;
    int ks   = g / 3;
    const float* W = (p == 0) ? Wq : ((p == 1) ? Wk : Wv);
    int n  = t2 * 32 + (lane & 31);
    int k0 = ks * 16 + (lane >> 5) * 8;
    f16x8 frag;
#pragma unroll
    for (int j = 0; j < 8; ++j) frag[j] = (f16)W[(k0 + j) * HH + n];
    ((f16x8*)wf)[t] = frag;
}

static __device__ __forceinline__ f16x8 cvt8(float4 f0, float4 f1) {
    f16x8 h;
    h[0]=(f16)f0.x; h[1]=(f16)f0.y; h[2]=(f16)f0.z; h[3]=(f16)f0.w;
    h[4]=(f16)f1.x; h[5]=(f16)f1.y; h[6]=(f16)f1.z; h[7]=(f16)f1.w;
    return h;
}

// async global->LDS DMA, 16 B per lane; LDS dest = wave-uniform base + lane*16
static __device__ __forceinline__ void glds16(const void* g, void* l) {
    __builtin_amdgcn_global_load_lds(
        (const __attribute__((address_space(1))) uint32_t*)g,
        (__attribute__((address_space(3))) uint32_t*)l, 16, 0, 0);
}

// 256 threads / 4 waves / 2 batches per block. Wave w owns 32 rows
// (rows w*32..+31 of the 128-row block) and computes all 192 qkv cols via
// SIX 32x32x16 MFMA accumulators: halves LDS B-read traffic per FLOP vs
// the 16x16 version (the measured DS-pipe bottleneck). LDS 55296 B ->
// 2 blocks/CU; 8 barriers per block total.
__launch_bounds__(256, 2)
__global__ void attn_head(const float* __restrict__ x,
                          const f16* __restrict__ wf,
                          float* __restrict__ out) {
    // arenas: [qsA ksmA vstA qsB ksmB vstB] x 4608 f16 = 55296 B.
    // W double buffer (2*24576 = 49152 B) overlays the front during projection.
    __shared__ __align__(16) char smem[6 * ARENA * sizeof(f16)];
    f16* wbuf = (f16*)smem;

    const int tid  = threadIdx.x;
    const int wave = tid >> 6;        // 0..3
    const int lane = tid & 63;
    const int l31  = lane & 31;
    const int lhi  = lane >> 5;       // 0/1
    const int quad = lane >> 4;
    const int cl   = lane & 15;

    const floatx16 az = {0.f,0.f,0.f,0.f,0.f,0.f,0.f,0.f,
                         0.f,0.f,0.f,0.f,0.f,0.f,0.f,0.f};
    floatx16 acc[6];
#pragma unroll
    for (int T = 0; T < 6; ++T) acc[T] = az;

    // lane's x A-frag source (32x32x16 A layout: row = lane&31, k-octet = lane>>5)
    const float* xp = x + ((size_t)blockIdx.x * 128 + wave * 32 + l31) * CDIM + lhi * 8;
    const char* wb  = (const char*)wf;

    // ---- prologue: DMA chunk 0 {6 ops}, then x(0) {8 ops}; order pinned ----
    float4 xa[2][4], xb[2][4];
#pragma unroll
    for (int j = 0; j < 6; ++j)
        glds16(wb + j * 4096 + tid * 16, wbuf + j * 2048 + wave * 512);
    asm volatile("" ::: "memory");
#pragma unroll
    for (int s = 0; s < 4; ++s) {
        xa[0][s] = *(const float4*)(xp + s * 16);
        xb[0][s] = *(const float4*)(xp + s * 16 + 4);
    }
    asm volatile("" ::: "memory");

    // ---- main loop: BK=64, counted vmcnt. At top of iter kk outstanding =
    //      [DMA(kk){6}, x(kk){8}] -> vmcnt(8) retires exactly DMA(kk).
#pragma unroll
    for (int kk = 0; kk < NKK; ++kk) {
        asm volatile("s_waitcnt vmcnt(8)" ::: "memory");
        __builtin_amdgcn_s_barrier();     // chunk kk published; other buf free
        if (kk + 1 < NKK) {
            const int nb = (kk + 1) & 1;
#pragma unroll
            for (int j = 0; j < 6; ++j)
                glds16(wb + (kk + 1) * CHUNKB + j * 4096 + tid * 16,
                       wbuf + nb * CHH + j * 2048 + wave * 512);
            asm volatile("" ::: "memory");
#pragma unroll
            for (int s = 0; s < 4; ++s) {
                xa[nb][s] = *(const float4*)(xp + (kk + 1) * 64 + s * 16);
                xb[nb][s] = *(const float4*)(xp + (kk + 1) * 64 + s * 16 + 4);
            }
            asm volatile("" ::: "memory");
        }
        const int cur = kk & 1;
        const f16* wc = wbuf + cur * CHH;
        __builtin_amdgcn_s_setprio(1);
#pragma unroll
        for (int ks = 0; ks < 4; ++ks) {
            f16x8 af = cvt8(xa[cur][ks], xb[cur][ks]);   // reg-dep waits by compiler
#pragma unroll
            for (int T = 0; T < 6; ++T) {
                f16x8 bf = *(const f16x8*)&wc[((ks * 6 + T) * 64 + lane) * 8];
                acc[T] = __builtin_amdgcn_mfma_f32_32x32x16_f16(af, bf, acc[T], 0, 0, 0);
            }
        }
        __builtin_amdgcn_s_setprio(0);
    }
    __syncthreads();                     // barrier D: W reads retired -> arena overlay safe

    // ---- spill into this batch's arenas (q pre-scaled, k [t][h], v^T [h][t]) ----
    // 32x32 C/D layout [m74/m101]: col = lane&31 (within tile),
    // row = (reg&3) + 8*(reg>>2) + 4*(lane>>5).
    const int bb  = wave >> 1;           // batch half 0/1
    const int rb0 = (wave & 1) * 32;     // wave's row base within its batch
    f16* qs  = (f16*)smem + bb * 3 * ARENA;
    f16* ksm = qs + ARENA;
    f16* vst = qs + 2 * ARENA;
    f16* ps  = qs;                       // overlays qs: own-wave rows only
    const int hv = 4 * lhi;
#pragma unroll
    for (int T = 0; T < 6; ++T) {
        const int p = T >> 1;
        const int h = (T & 1) * 32 + l31;
        if (p == 2) {
#pragma unroll
            for (int g = 0; g < 4; ++g) {
                f16x4 vv;
#pragma unroll
                for (int i = 0; i < 4; ++i) vv[i] = (f16)acc[T][g * 4 + i];
                *(f16x4*)&vst[h * LDP + rb0 + g * 8 + hv] = vv;
            }
        } else if (p == 0) {             // q: fold in SCALE here
#pragma unroll
            for (int g = 0; g < 4; ++g)
#pragma unroll
                for (int i = 0; i < 4; ++i)
                    qs[(rb0 + g * 8 + hv + i) * LDP + h] = (f16)(acc[T][g * 4 + i] * SCALE);
        } else {
#pragma unroll
            for (int g = 0; g < 4; ++g)
#pragma unroll
                for (int i = 0; i < 4; ++i)
                    ksm[(rb0 + g * 8 + hv + i) * LDP + h] = (f16)acc[T][g * 4 + i];
        }
    }
    __syncthreads();                     // barrier A: ksm/vst published

    // ---- attention tail: verified 16x16 path, two 16-row groups per wave ----
    const floatx4 fzero = {0.f, 0.f, 0.f, 0.f};
    const size_t obase = ((size_t)blockIdx.x * 2 + bb) * (TT * HH);
    f16x8 ones;
#pragma unroll
    for (int j = 0; j < 8; ++j) ones[j] = (f16)1.0f;

#pragma unroll
    for (int g2 = 0; g2 < 2; ++g2) {
        const int row0 = rb0 + g2 * 16;

        // S = (q*SCALE) k^T
        floatx4 sa[4];
#pragma unroll
        for (int t = 0; t < 4; ++t) sa[t] = fzero;
#pragma unroll
        for (int kv = 0; kv < 2; ++kv) {
            f16x8 aq = *(const f16x8*)&qs[(row0 + cl) * LDP + kv * 32 + quad * 8];
#pragma unroll
            for (int t = 0; t < 4; ++t) {
                f16x8 bk = *(const f16x8*)&ksm[(t * 16 + cl) * LDP + kv * 32 + quad * 8];
                sa[t] = __builtin_amdgcn_mfma_f32_16x16x32_f16(aq, bk, sa[t], 0, 0, 0);
            }
        }

        // P = exp(S) masked, UNNORMALIZED; ps overlays qs own-wave rows only
        // (group g2 writes rows row0..row0+15; group 1's qs reads are rows
        //  rb0+16..31, untouched by group 0's writes)
#pragma unroll
        for (int t = 0; t < 4; ++t) {
            int s = t * 16 + cl;
#pragma unroll
            for (int r = 0; r < 4; ++r) {
                int tr = row0 + quad * 4 + r;
                float p = (s <= tr) ? __expf(sa[t][r]) : 0.0f;
                ps[tr * LDP + s] = (f16)p;
            }
        }

        // O_unnorm = P V ; den = P * ones (own-row ps reads: in-order DS pipe)
        floatx4 oa[4];
        floatx4 den = fzero;
#pragma unroll
        for (int t = 0; t < 4; ++t) oa[t] = fzero;
#pragma unroll
        for (int kv = 0; kv < 2; ++kv) {
            f16x8 ap = *(const f16x8*)&ps[(row0 + cl) * LDP + kv * 32 + quad * 8];
            den = __builtin_amdgcn_mfma_f32_16x16x32_f16(ap, ones, den, 0, 0, 0);
#pragma unroll
            for (int t = 0; t < 4; ++t) {
                f16x8 bv = *(const f16x8*)&vst[(t * 16 + cl) * LDP + kv * 32 + quad * 8];
                oa[t] = __builtin_amdgcn_mfma_f32_16x16x32_f16(ap, bv, oa[t], 0, 0, 0);
            }
        }
        float rden[4];
#pragma unroll
        for (int r = 0; r < 4; ++r) rden[r] = 1.0f / den[r];

        // direct stores: 16 lanes x 4B = 64 B segments, 4 rows per instr
        float* op = out + obase;
#pragma unroll
        for (int t = 0; t < 4; ++t)
#pragma unroll
            for (int r = 0; r < 4; ++r)
                op[(row0 + quad * 4 + r) * HH + t * 16 + cl] = oa[t][r] * rden[r];
    }
}

extern "C" void kernel_launch(void* const* d_in, const int* in_sizes, int n_in,
                              void* d_out, int out_size, void* d_ws, size_t ws_size,
                              hipStream_t stream) {
    const float* x  = (const float*)d_in[0];
    const float* Wq = (const float*)d_in[1];
    const float* Wk = (const float*)d_in[2];
    const float* Wv = (const float*)d_in[3];
    float* out = (float*)d_out;
    f16* wf = (f16*)d_ws;   // 24*3*2*64*16 = 147456 bytes

    prep_w<<<36, 256, 0, stream>>>(Wq, Wk, Wv, wf);
    attn_head<<<1024, 256, 0, stream>>>(x, wf, out);
}